// Round 2
// baseline (105.255 us; speedup 1.0000x reference)
//
#include <hip/hip_runtime.h>
#include <hip/hip_bf16.h>

// f(x) = w3 · gelu(W2 · gelu(w1·x + b1) + b2) + b3  — a fixed scalar->scalar map.
// Strategy: kernel 1 tabulates f on a 4096-interval grid over [-6.5, 6.5] into d_ws;
// kernel 2 streams x -> out via LDS-resident LUT + linear interpolation (memory-bound).
// Out-of-range lanes (never occurs for N(0,1) inputs) fall back to exact evaluation.

#define N_LUT 4096
#define LUT_LO -6.5f
#define LUT_HI 6.5f

__device__ __forceinline__ float gelu_exact(float z) {
    // exact gelu: 0.5*z*(1+erf(z/sqrt(2)))
    return 0.5f * z * (1.0f + erff(z * 0.70710678118654752440f));
}

__device__ float mlp_exact(float x,
                           const float* __restrict__ w1, const float* __restrict__ b1,
                           const float* __restrict__ w2, const float* __restrict__ b2,
                           const float* __restrict__ w3, float b3s) {
    float h1[16];
#pragma unroll
    for (int i = 0; i < 16; ++i)
        h1[i] = gelu_exact(fmaf(x, w1[i], b1[i]));
    float acc = b3s;
    for (int o = 0; o < 16; ++o) {
        float z = b2[o];
#pragma unroll
        for (int h = 0; h < 16; ++h)
            z = fmaf(h1[h], w2[o * 16 + h], z);   // w2 is (out=16, in=16) row-major
        acc = fmaf(gelu_exact(z), w3[o], acc);     // w3 is (1,16)
    }
    return acc;
}

__global__ void __launch_bounds__(256)
build_lut_kernel(float* __restrict__ lut,
                 const float* __restrict__ w1, const float* __restrict__ b1,
                 const float* __restrict__ w2, const float* __restrict__ b2,
                 const float* __restrict__ w3, const float* __restrict__ b3) {
    int i = blockIdx.x * blockDim.x + threadIdx.x;
    if (i > N_LUT) return;  // N_LUT+1 samples, inclusive endpoints
    float x = LUT_LO + (LUT_HI - LUT_LO) * ((float)i / (float)N_LUT);
    lut[i] = mlp_exact(x, w1, b1, w2, b2, w3, b3[0]);
}

__global__ void __launch_bounds__(256)
apply_kernel(const float4* __restrict__ x4, float4* __restrict__ out4,
             const float* __restrict__ g_lut, int n4, int tail, int n_total,
             const float* __restrict__ x_s, float* __restrict__ out_s,
             const float* __restrict__ w1, const float* __restrict__ b1,
             const float* __restrict__ w2, const float* __restrict__ b2,
             const float* __restrict__ w3, const float* __restrict__ b3) {
    __shared__ float lut[N_LUT + 1];
    for (int i = threadIdx.x; i <= N_LUT; i += blockDim.x)
        lut[i] = g_lut[i];
    __syncthreads();

    const float scale = (float)N_LUT / (LUT_HI - LUT_LO);
    const int stride = gridDim.x * blockDim.x;
    for (int idx = blockIdx.x * blockDim.x + threadIdx.x; idx < n4; idx += stride) {
        float4 v = x4[idx];
        float in[4] = {v.x, v.y, v.z, v.w};
        float r[4];
#pragma unroll
        for (int j = 0; j < 4; ++j) {
            float xv = in[j];
            if (xv >= LUT_LO && xv <= LUT_HI) {
                float t = (xv - LUT_LO) * scale;
                int i = (int)t;
                if (i > N_LUT - 1) i = N_LUT - 1;
                float frac = t - (float)i;
                float lo = lut[i], hi = lut[i + 1];
                r[j] = fmaf(frac, hi - lo, lo);
            } else {
                // essentially never taken for N(0,1) inputs; exact fallback
                r[j] = mlp_exact(xv, w1, b1, w2, b2, w3, b3[0]);
            }
        }
        out4[idx] = make_float4(r[0], r[1], r[2], r[3]);
    }

    // scalar tail (out_size % 4), exact path; trivial count
    if (blockIdx.x == 0 && (int)threadIdx.x < tail) {
        int i = n4 * 4 + threadIdx.x;
        out_s[i] = mlp_exact(x_s[i], w1, b1, w2, b2, w3, b3[0]);
    }
}

extern "C" void kernel_launch(void* const* d_in, const int* in_sizes, int n_in,
                              void* d_out, int out_size, void* d_ws, size_t ws_size,
                              hipStream_t stream) {
    const float* x  = (const float*)d_in[0];
    const float* w1 = (const float*)d_in[1];
    const float* b1 = (const float*)d_in[2];
    const float* w2 = (const float*)d_in[3];
    const float* b2 = (const float*)d_in[4];
    const float* w3 = (const float*)d_in[5];
    const float* b3 = (const float*)d_in[6];
    float* out = (float*)d_out;
    float* lut = (float*)d_ws;  // (N_LUT+1) floats = 16.4 KB scratch

    // Kernel 1: tabulate f (tiny)
    build_lut_kernel<<<(N_LUT + 1 + 255) / 256, 256, 0, stream>>>(
        lut, w1, b1, w2, b2, w3, b3);

    // Kernel 2: stream x -> out through the LUT
    int n4 = out_size >> 2;
    int tail = out_size & 3;
    int grid = 2048;  // 8 blocks/CU over 256 CUs; grid-stride covers n4
    apply_kernel<<<grid, 256, 0, stream>>>(
        (const float4*)x, (float4*)out, lut, n4, tail, out_size,
        x, out, w1, b1, w2, b2, w3, b3);
}